// Round 1
// baseline (599.212 us; speedup 1.0000x reference)
//
#include <hip/hip_runtime.h>
#include <math.h>

// Problem constants (fixed by the reference's shapes)
#define NROWS   131072      // 32*64*64 spatial positions
#define DFEAT   64          // feature dim (C)
#define KHALF   512         // rows per embedding table
#define HW      4096        // 64*64
#define CHW     262144      // 64*4096
#define CHUNK   128         // codes staged per LDS chunk
#define NQOUT   8388608     // 32*64*64*64 quantized elements

// ---------------------------------------------------------------------------
// Kernel 0: per-code squared norms into ws.  cn[k] = ||codes[k]||^2, k<1024.
// ---------------------------------------------------------------------------
__global__ void vq_cnorm(const float* __restrict__ e0, const float* __restrict__ e1,
                         const float* __restrict__ e2, const int* __restrict__ idxp,
                         float* __restrict__ cn) {
    int k = blockIdx.x * blockDim.x + threadIdx.x;
    if (k >= 1024) return;
    int idx = idxp[0];
    const float* sel = (idx == 2) ? e2 : e1;
    const float* row = (k < KHALF) ? (e0 + (size_t)k * DFEAT)
                                   : (sel + (size_t)(k - KHALF) * DFEAT);
    float s = 0.f;
#pragma unroll
    for (int c = 0; c < DFEAT; ++c) s = fmaf(row[c], row[c], s);
    cn[k] = s;
}

// ---------------------------------------------------------------------------
// Kernel 1: main VQ.  One thread per spatial row.  Block = 256 rows.
// ---------------------------------------------------------------------------
__global__ void vq_main(const float* __restrict__ x,
                        const float* __restrict__ e0, const float* __restrict__ e1,
                        const float* __restrict__ e2, const int* __restrict__ idxp,
                        const float* __restrict__ cn_g,
                        float* __restrict__ out, float* __restrict__ loss_acc,
                        int* __restrict__ hist) {
    __shared__ float cs[CHUNK * DFEAT];   // 32 KB code chunk
    __shared__ float cn_s[CHUNK];

    const int t    = threadIdx.x;
    const int r0   = blockIdx.x * 256;
    const int n    = r0 >> 12;            // 4096 rows per image; 256 | 4096
    const int rem0 = r0 & 4095;

    // --- load this thread's x row (coalesced across lanes for each c) ---
    const float* xin = x + (size_t)n * CHW + rem0;
    float xr[DFEAT];
#pragma unroll
    for (int c = 0; c < DFEAT; ++c) xr[c] = xin[(size_t)c * HW + t];

    const int idx = idxp[0];
    const float* sel = (idx == 2) ? e2 : e1;
    const int nch = (idx == 0) ? 4 : 8;   // 4 chunks = 512 codes, 8 = 1024

    float best  = 3.4e38f;
    int   bestk = 0;

    for (int ch = 0; ch < nch; ++ch) {
        __syncthreads();
        // stage 128 contiguous code rows (8192 floats) into LDS, coalesced
        const float* src = (ch < 4) ? (e0 + ch * (CHUNK * DFEAT))
                                    : (sel + (ch - 4) * (CHUNK * DFEAT));
        const float4* g4 = (const float4*)src;
        float4* cs4w = (float4*)cs;
#pragma unroll
        for (int i = 0; i < 8; ++i) cs4w[i * 256 + t] = g4[i * 256 + t];
        if (t < CHUNK) cn_s[t] = cn_g[ch * CHUNK + t];
        __syncthreads();

        const float4* cs4 = (const float4*)cs;
        for (int k = 0; k < CHUNK; k += 2) {
            float a0 = 0.f, b0 = 0.f, a1 = 0.f, b1 = 0.f;
#pragma unroll
            for (int j = 0; j < 16; j += 2) {
                float4 c00 = cs4[(k << 4) + j];
                float4 c01 = cs4[(k << 4) + j + 1];
                float4 c10 = cs4[(k << 4) + 16 + j];
                float4 c11 = cs4[(k << 4) + 16 + j + 1];
                const int d0 = 4 * j;
                a0 = fmaf(xr[d0 + 0], c00.x, a0);
                a0 = fmaf(xr[d0 + 1], c00.y, a0);
                a0 = fmaf(xr[d0 + 2], c00.z, a0);
                a0 = fmaf(xr[d0 + 3], c00.w, a0);
                b0 = fmaf(xr[d0 + 4], c01.x, b0);
                b0 = fmaf(xr[d0 + 5], c01.y, b0);
                b0 = fmaf(xr[d0 + 6], c01.z, b0);
                b0 = fmaf(xr[d0 + 7], c01.w, b0);
                a1 = fmaf(xr[d0 + 0], c10.x, a1);
                a1 = fmaf(xr[d0 + 1], c10.y, a1);
                a1 = fmaf(xr[d0 + 2], c10.z, a1);
                a1 = fmaf(xr[d0 + 3], c10.w, a1);
                b1 = fmaf(xr[d0 + 4], c11.x, b1);
                b1 = fmaf(xr[d0 + 5], c11.y, b1);
                b1 = fmaf(xr[d0 + 6], c11.z, b1);
                b1 = fmaf(xr[d0 + 7], c11.w, b1);
            }
            // dist = ||c||^2 - 2 x.c   (||x||^2 is row-constant: argmin-invariant)
            float dist0 = fmaf(-2.f, a0 + b0, cn_s[k]);
            float dist1 = fmaf(-2.f, a1 + b1, cn_s[k + 1]);
            const int kb = (ch << 7) + k;
            if (dist0 < best) { best = dist0; bestk = kb; }       // strict <: first-index ties
            if (dist1 < best) { best = dist1; bestk = kb + 1; }
        }
    }

    // --- epilogue: gather chosen code, write out (coalesced), loss, histogram ---
    const float* cp = (bestk < KHALF) ? (e0 + (size_t)bestk * DFEAT)
                                      : (sel + (size_t)(bestk - KHALF) * DFEAT);
    float* outp = out + (size_t)n * CHW + rem0;
    float lsum = 0.f;
#pragma unroll
    for (int c = 0; c < DFEAT; ++c) {
        float qv = cp[c];
        float df = qv - xr[c];
        lsum = fmaf(df, df, lsum);
        outp[(size_t)c * HW + t] = qv;
    }
#pragma unroll
    for (int off = 32; off > 0; off >>= 1) lsum += __shfl_down(lsum, off, 64);
    if ((t & 63) == 0) atomicAdd(loss_acc, lsum);
    atomicAdd(&hist[bestk], 1);
}

// ---------------------------------------------------------------------------
// Kernel 2: finalize — loss scalar + perplexity from histogram. One block.
// ---------------------------------------------------------------------------
__global__ void vq_finalize(const float* __restrict__ wsf, const int* __restrict__ hist,
                            float* __restrict__ out) {
    __shared__ double partial[16];
    const int t = threadIdx.x;          // 1024 threads, one per bin
    double p = (double)hist[t] / (double)NROWS;
    double term = p * log(p + 1e-10);   // p==0 -> exactly 0
#pragma unroll
    for (int off = 32; off > 0; off >>= 1) term += __shfl_down(term, off, 64);
    if ((t & 63) == 0) partial[t >> 6] = term;
    __syncthreads();
    if (t == 0) {
        double s = 0.0;
        for (int i = 0; i < 16; ++i) s += partial[i];
        out[NQOUT + 1] = (float)exp(-s);                       // perplexity
        out[NQOUT]     = 1.25f * (wsf[0] / (float)NQOUT);      // q_loss + 0.25*e_loss
    }
}

// ---------------------------------------------------------------------------
extern "C" void kernel_launch(void* const* d_in, const int* in_sizes, int n_in,
                              void* d_out, int out_size, void* d_ws, size_t ws_size,
                              hipStream_t stream) {
    const float* x  = (const float*)d_in[0];
    const float* e0 = (const float*)d_in[1];
    const float* e1 = (const float*)d_in[2];
    const float* e2 = (const float*)d_in[3];
    const int* idxp = (const int*)d_in[4];
    float* out = (float*)d_out;

    // ws layout: [0] loss accum (f32) | [256..1280) hist (1024 i32) | [2048..3072) cn (1024 f32)
    float* wsf      = (float*)d_ws;
    float* loss_acc = wsf;
    int*   hist     = (int*)(wsf + 256);
    float* cn       = wsf + 2048;

    hipMemsetAsync(d_ws, 0, 3072 * sizeof(float), stream);
    vq_cnorm<<<4, 256, 0, stream>>>(e0, e1, e2, idxp, cn);
    vq_main<<<NROWS / 256, 256, 0, stream>>>(x, e0, e1, e2, idxp, cn, out, loss_acc, hist);
    vq_finalize<<<1, 1024, 0, stream>>>(wsf, hist, out);
}

// Round 2
// 194.143 us; speedup vs baseline: 3.0865x; 3.0865x over previous
//
#include <hip/hip_runtime.h>
#include <math.h>

// Problem constants (fixed by the reference's shapes)
#define NROWS   131072      // 32*64*64 spatial positions
#define DFEAT   64          // feature dim (C)
#define KHALF   512         // rows per embedding table
#define HW      4096        // 64*64
#define CHW     262144      // 64*4096
#define NQOUT   8388608     // 32*64*64*64 quantized elements

typedef __attribute__((ext_vector_type(8))) short   bf16x8;
typedef __attribute__((ext_vector_type(4))) float   f32x4;

__device__ __forceinline__ unsigned short f2bf(float f) {
    unsigned int u = __float_as_uint(f);
    u += 0x7FFFu + ((u >> 16) & 1u);          // round-to-nearest-even
    return (unsigned short)(u >> 16);
}
__device__ __forceinline__ float bf2f(unsigned short h) {
    return __uint_as_float(((unsigned int)h) << 16);
}

// ---------------------------------------------------------------------------
// Kernel 0: cnh[k] = 0.5 * ||codes[k]||^2  (fp32 exact), k < 1024
// ---------------------------------------------------------------------------
__global__ void vq_cnorm(const float* __restrict__ e0, const float* __restrict__ e1,
                         const float* __restrict__ e2, const int* __restrict__ idxp,
                         float* __restrict__ cnh) {
    int k = blockIdx.x * blockDim.x + threadIdx.x;
    if (k >= 1024) return;
    int idx = idxp[0];
    const float* sel = (idx == 2) ? e2 : e1;
    const float* row = (k < KHALF) ? (e0 + (size_t)k * DFEAT)
                                   : (sel + (size_t)(k - KHALF) * DFEAT);
    float s = 0.f;
#pragma unroll
    for (int c = 0; c < DFEAT; ++c) s = fmaf(row[c], row[c], s);
    cnh[k] = 0.5f * s;
}

// ---------------------------------------------------------------------------
// Kernel 1: pack codes into MFMA-B-fragment order, hi/lo bf16 split.
// Layout: fragbuf[tile(64)][frag(4)][lane(64)][j(8)] ushort
//   frag 0: hi, k=0..31    frag 1: hi, k=32..63
//   frag 2: lo, k=0..31    frag 3: lo, k=32..63
// lane L of frag f holds code (tile*16 + (L&15)), feats kb..kb+7,
//   kb = (f&1)*32 + (L>>4)*8    -> ready for mfma_f32_16x16x32_bf16 B operand
// ---------------------------------------------------------------------------
__global__ void vq_pack(const float* __restrict__ e0, const float* __restrict__ e1,
                        const float* __restrict__ e2, const int* __restrict__ idxp,
                        unsigned short* __restrict__ fragbuf) {
    int tau = blockIdx.x * 256 + threadIdx.x;   // 64 blocks * 256 = 16384
    int tile = tau >> 8;
    int rem  = tau & 255;
    int f    = rem >> 6;
    int L    = rem & 63;
    int code = tile * 16 + (L & 15);
    int kb   = (f & 1) * 32 + (L >> 4) * 8;
    int lo_f = f >> 1;
    int idx  = idxp[0];
    const float* sel = (idx == 2) ? e2 : e1;
    const float* src = (code < KHALF) ? (e0 + (size_t)code * DFEAT)
                                      : (sel + (size_t)(code - KHALF) * DFEAT);
    unsigned short* dst = fragbuf + (size_t)tau * 8;
#pragma unroll
    for (int j = 0; j < 8; ++j) {
        float v = src[kb + j];
        unsigned short hb = f2bf(v);
        dst[j] = lo_f ? f2bf(v - bf2f(hb)) : hb;
    }
}

// ---------------------------------------------------------------------------
// Kernel 2: main VQ. Block = 256 threads = 4 waves; 64 rows per wave
// (4 MFMA row-tiles of 16), all 1024 codes streamed as B fragments from L2.
// ---------------------------------------------------------------------------
__global__ __launch_bounds__(256, 2) void vq_main(
        const float* __restrict__ x,
        const float* __restrict__ e0, const float* __restrict__ e1,
        const float* __restrict__ e2, const int* __restrict__ idxp,
        const float* __restrict__ cnh, const unsigned short* __restrict__ fragbuf,
        float* __restrict__ out, float* __restrict__ loss_acc,
        int* __restrict__ hist) {
    __shared__ float xsq_s[256];
    __shared__ float sc_s[256];
    __shared__ int   bk_s[256];

    const int t = threadIdx.x;
    const int w = t >> 6;          // wave in block
    const int L = t & 63;          // lane
    const int q = L >> 4;          // quad
    const int m = L & 15;

    const int rowbase = blockIdx.x * 256;   // 512 blocks; never straddles an image
    const int n  = rowbase >> 12;
    const int s0 = rowbase & 4095;

    const int idx = idxp[0];
    const float* sel = (idx == 2) ? e2 : e1;
    const int ntiles = (idx == 0) ? 32 : 64;

    // ---- A fragments: 4 row-tiles of 16 rows, hi/lo bf16 + ||x||^2 ----
    bf16x8 ahi[4][2], alo[4][2];
    const float* xb = x + (size_t)n * CHW + (s0 + w * 64);
#pragma unroll
    for (int rt = 0; rt < 4; ++rt) {
        const float* xr = xb + rt * 16 + m;
        float xs = 0.f;
#pragma unroll
        for (int h = 0; h < 2; ++h) {
#pragma unroll
            for (int j = 0; j < 8; ++j) {
                int c = h * 32 + q * 8 + j;
                float v = xr[(size_t)c * HW];
                xs = fmaf(v, v, xs);
                unsigned short hb = f2bf(v);
                unsigned short lb = f2bf(v - bf2f(hb));
                ahi[rt][h][j] = (short)hb;
                alo[rt][h][j] = (short)lb;
            }
        }
        // full ||x_row||^2: row features live in lanes {m, m+16, m+32, m+48}
        xs += __shfl_xor(xs, 16, 64);
        xs += __shfl_xor(xs, 32, 64);
        if (q == 0) xsq_s[w * 64 + rt * 16 + m] = xs;
    }

    // ---- stream 64 code tiles; score = x.c - 0.5||c||^2, argMAX ----
    const bf16x8* fb = (const bf16x8*)fragbuf;
    float best[16];
    int   bidx[16];
#pragma unroll
    for (int i = 0; i < 16; ++i) { best[i] = -3.4e38f; bidx[i] = 0; }

    bf16x8 bc0 = fb[0 * 64 + L];
    bf16x8 bc1 = fb[1 * 64 + L];
    bf16x8 bc2 = fb[2 * 64 + L];
    bf16x8 bc3 = fb[3 * 64 + L];
    float  cnc = cnh[m];

    for (int tt = 0; tt < ntiles; ++tt) {
        const int tn = (tt + 1 < ntiles) ? tt + 1 : tt;
        bf16x8 bn0 = fb[(tn * 4 + 0) * 64 + L];
        bf16x8 bn1 = fb[(tn * 4 + 1) * 64 + L];
        bf16x8 bn2 = fb[(tn * 4 + 2) * 64 + L];
        bf16x8 bn3 = fb[(tn * 4 + 3) * 64 + L];
        float  cnn = cnh[tn * 16 + m];
        const int kt = tt * 16 + m;    // this lane's candidate code id (col = m)
#pragma unroll
        for (int rt = 0; rt < 4; ++rt) {
            f32x4 acc = {0.f, 0.f, 0.f, 0.f};
            acc = __builtin_amdgcn_mfma_f32_16x16x32_bf16(ahi[rt][0], bc0, acc, 0, 0, 0); // hi*hi
            acc = __builtin_amdgcn_mfma_f32_16x16x32_bf16(ahi[rt][1], bc1, acc, 0, 0, 0);
            acc = __builtin_amdgcn_mfma_f32_16x16x32_bf16(ahi[rt][0], bc2, acc, 0, 0, 0); // hi*lo
            acc = __builtin_amdgcn_mfma_f32_16x16x32_bf16(ahi[rt][1], bc3, acc, 0, 0, 0);
            acc = __builtin_amdgcn_mfma_f32_16x16x32_bf16(alo[rt][0], bc0, acc, 0, 0, 0); // lo*hi
            acc = __builtin_amdgcn_mfma_f32_16x16x32_bf16(alo[rt][1], bc1, acc, 0, 0, 0);
            acc = __builtin_amdgcn_mfma_f32_16x16x32_bf16(alo[rt][0], bc2, acc, 0, 0, 0); // lo*lo
            acc = __builtin_amdgcn_mfma_f32_16x16x32_bf16(alo[rt][1], bc3, acc, 0, 0, 0);
#pragma unroll
            for (int r = 0; r < 4; ++r) {
                float s = acc[r] - cnc;
                if (s > best[rt * 4 + r]) { best[rt * 4 + r] = s; bidx[rt * 4 + r] = kt; }
            }
        }
        bc0 = bn0; bc1 = bn1; bc2 = bn2; bc3 = bn3; cnc = cnn;
    }

    // ---- reduce argmax across the 16 cols (lane bits 0-3) ----
#pragma unroll
    for (int i = 0; i < 16; ++i) {
        float b = best[i]; int k = bidx[i];
#pragma unroll
        for (int off = 1; off < 16; off <<= 1) {
            float ob = __shfl_xor(b, off, 64);
            int   ok = __shfl_xor(k, off, 64);
            if (ob > b || (ob == b && ok < k)) { b = ob; k = ok; }
        }
        if (m == 0) {   // D row = q*4 + r within tile rt
            int row = w * 64 + (i >> 2) * 16 + q * 4 + (i & 3);
            sc_s[row] = b; bk_s[row] = k;
        }
    }
    __syncthreads();

    // ---- epilogue: one thread per row ----
    const int k   = bk_s[t];
    float dist    = xsq_s[t] - 2.f * sc_s[t];   // ||x||^2 - 2x.c + ||c||^2
    float l = dist;
#pragma unroll
    for (int off = 32; off > 0; off >>= 1) l += __shfl_down(l, off, 64);
    if (L == 0) atomicAdd(loss_acc, l);
    atomicAdd(&hist[k], 1);

    const float* cp = (k < KHALF) ? (e0 + (size_t)k * DFEAT)
                                  : (sel + (size_t)(k - KHALF) * DFEAT);
    const float4* cp4 = (const float4*)cp;
    float* op = out + (size_t)n * CHW + (s0 + t);
#pragma unroll
    for (int c4 = 0; c4 < 16; ++c4) {
        float4 v = cp4[c4];
        op[(size_t)(4 * c4 + 0) * HW] = v.x;
        op[(size_t)(4 * c4 + 1) * HW] = v.y;
        op[(size_t)(4 * c4 + 2) * HW] = v.z;
        op[(size_t)(4 * c4 + 3) * HW] = v.w;
    }
}

// ---------------------------------------------------------------------------
// Kernel 3: finalize — loss scalar + perplexity from histogram. One block.
// ---------------------------------------------------------------------------
__global__ void vq_finalize(const float* __restrict__ wsf, const int* __restrict__ hist,
                            float* __restrict__ out) {
    __shared__ double partial[16];
    const int t = threadIdx.x;          // 1024 threads, one per bin
    double p = (double)hist[t] / (double)NROWS;
    double term = p * log(p + 1e-10);   // p==0 -> exactly 0
#pragma unroll
    for (int off = 32; off > 0; off >>= 1) term += __shfl_down(term, off, 64);
    if ((t & 63) == 0) partial[t >> 6] = term;
    __syncthreads();
    if (t == 0) {
        double s = 0.0;
        for (int i = 0; i < 16; ++i) s += partial[i];
        out[NQOUT + 1] = (float)exp(-s);                       // perplexity
        out[NQOUT]     = 1.25f * (wsf[0] / (float)NQOUT);      // q_loss + 0.25*e_loss
    }
}

// ---------------------------------------------------------------------------
extern "C" void kernel_launch(void* const* d_in, const int* in_sizes, int n_in,
                              void* d_out, int out_size, void* d_ws, size_t ws_size,
                              hipStream_t stream) {
    const float* x  = (const float*)d_in[0];
    const float* e0 = (const float*)d_in[1];
    const float* e1 = (const float*)d_in[2];
    const float* e2 = (const float*)d_in[3];
    const int* idxp = (const int*)d_in[4];
    float* out = (float*)d_out;

    // ws layout (floats): [0] loss | [256..1280) hist | [2048..3072) cnh
    //                     [4096..) fragbuf: 131072 ushort = 256 KB
    float* wsf      = (float*)d_ws;
    float* loss_acc = wsf;
    int*   hist     = (int*)(wsf + 256);
    float* cnh      = wsf + 2048;
    unsigned short* fragbuf = (unsigned short*)(wsf + 4096);

    hipMemsetAsync(d_ws, 0, 1280 * sizeof(float), stream);
    vq_cnorm<<<4, 256, 0, stream>>>(e0, e1, e2, idxp, cnh);
    vq_pack<<<64, 256, 0, stream>>>(e0, e1, e2, idxp, fragbuf);
    vq_main<<<NROWS / 256, 256, 0, stream>>>(x, e0, e1, e2, idxp, cnh, fragbuf,
                                             out, loss_acc, hist);
    vq_finalize<<<1, 1024, 0, stream>>>(wsf, hist, out);
}